// Round 4
// baseline (230.845 us; speedup 1.0000x reference)
//
#include <hip/hip_runtime.h>
#include <hip/hip_bf16.h>

// MHA forward: B=4, T=2048, N=1024, H=16, Dh=64.
// Round 13: bisect R11's NaN — remove ALL inline-asm v_cvt_pk_bf16_f32
// (suspected write->DPP/MFMA wait-state hazard invisible through asm);
// pack via proven v_perm pack_bf16x2. Keep:
//  - Q pre-scaled by 0.125*log2e in GEMM epilogue; p = exp2(z) directly.
//  - const-zero MFMA C operand kills z-init movs.
// LDS layout: R10-proven [2][64][8] + row&7 XOR staging.

typedef __attribute__((ext_vector_type(8))) short short8;   // 8 x bf16 (4 VGPR)
typedef __attribute__((ext_vector_type(4))) float f32x4;
typedef __attribute__((ext_vector_type(16))) float f32x16;

#define MFMA16(a, b, c) __builtin_amdgcn_mfma_f32_16x16x32_bf16((a), (b), (c), 0, 0, 0)
#define MFMA32(a, b, c) __builtin_amdgcn_mfma_f32_32x32x16_bf16((a), (b), (c), 0, 0, 0)

#if defined(__has_builtin)
#if __has_builtin(__builtin_amdgcn_exp2f)
#define EXP2(x) __builtin_amdgcn_exp2f(x)
#endif
#endif
#ifndef EXP2
#define EXP2(x) exp2f(x)
#endif

// async global->LDS, 16B per lane; LDS dest = wave-uniform base + lane*16
__device__ __forceinline__ void gload_lds16(const void* g, void* l) {
  __builtin_amdgcn_global_load_lds(
      (const __attribute__((address_space(1))) unsigned int*)g,
      (__attribute__((address_space(3))) unsigned int*)l, 16, 0, 0);
}

// pack two fp32 -> bf16x2 (round via bit bias + byte perm)
__device__ __forceinline__ unsigned pack_bf16x2(float lo, float hi) {
  unsigned ulo = __float_as_uint(lo) + 0x8000u;
  unsigned uhi = __float_as_uint(hi) + 0x8000u;
  return __builtin_amdgcn_perm(uhi, ulo, 0x07060302u);
}

__device__ __forceinline__ unsigned short bf16u(float f) {
  return (unsigned short)((__float_as_uint(f) + 0x8000u) >> 16);
}

// ---------------- elementwise fp32 -> bf16 ----------------
__global__ void conv_f32_bf16(const float* __restrict__ src,
                              unsigned* __restrict__ dst, int n4) {
  int i = blockIdx.x * blockDim.x + threadIdx.x;
  if (i >= n4) return;
  float4 v = ((const float4*)src)[i];
  uint2 o;
  o.x = pack_bf16x2(v.x, v.y);
  o.y = pack_bf16x2(v.z, v.w);
  ((uint2*)dst)[i] = o;
}

// ---------------- transpose + convert: dst[c][r] = bf16(src[r][c]) ----------------
__global__ void transpose_bf16(const float* __restrict__ src,
                               __hip_bfloat16* __restrict__ dst, int R, int C) {
  __shared__ float tile[32][33];
  int tx = threadIdx.x, ty = threadIdx.y;          // block (32, 8)
  int c0 = blockIdx.x * 32, r0 = blockIdx.y * 32;
#pragma unroll
  for (int i = 0; i < 32; i += 8)
    tile[ty + i][tx] = src[(long)(r0 + ty + i) * C + c0 + tx];
  __syncthreads();
#pragma unroll
  for (int i = 0; i < 32; i += 8)
    dst[(long)(c0 + ty + i) * R + r0 + tx] = __float2bfloat16(tile[tx][ty + i]);
}

// ---------------- GEMM: C[M,N] = A[M,K] @ Bt[N,K]^T + bias ----------------
// K-loop: m97 structure (barrier / global_load_lds / barrier / MFMA).
// Epilogue: C -> LDS (bias added; V-tiles transposed; Q scaled by 0.125*log2e)
// -> 16B coalesced stores.
template <int EPI>
__global__ __launch_bounds__(256, 2) void gemm_bt(
    const __hip_bfloat16* __restrict__ A, const __hip_bfloat16* __restrict__ Bt,
    const float* __restrict__ bias, void* o0, void* o1, void* o2, int N, int K) {
  __shared__ alignas(16) char smem[34816];
  short8 (*As)[8] = (short8(*)[8])smem;                        // [128][8]
  short8 (*Bs)[8] = (short8(*)[8])(smem + 16384);              // [128][8]
  unsigned short (*C16)[136] = (unsigned short(*)[136])smem;   // [128][136]
  float (*C32)[132] = (float(*)[132])smem;                     // [64][132]

  const int tid = threadIdx.x;
  const int lane = tid & 63, w = tid >> 6;
  const int l15 = lane & 15, quad = lane >> 4;
  const int wm = (w >> 1) * 64, wn = (w & 1) * 64;
  const int rowBase = blockIdx.y * 128;
  const int colBase = blockIdx.x * 128;
  const int sr8 = lane >> 3;                  // 0..7 within wave's 8-row slab
  const int scc = (lane & 7) ^ sr8;           // source chunk (dest chunk ^ row&7)

  f32x4 acc[4][4];
#pragma unroll
  for (int mi = 0; mi < 4; ++mi)
#pragma unroll
    for (int ni = 0; ni < 4; ++ni)
      acc[mi][ni] = {0.f, 0.f, 0.f, 0.f};

  for (int k0 = 0; k0 < K; k0 += 64) {
    __syncthreads();
#pragma unroll
    for (int p = 0; p < 4; ++p) {
      const int rb = p * 32 + w * 8;          // wave-uniform row base
      const int row = rb + sr8;
      gload_lds16(A + (rowBase + row) * K + k0 + scc * 8, &As[rb][0]);
      gload_lds16(Bt + (colBase + row) * K + k0 + scc * 8, &Bs[rb][0]);
    }
    __syncthreads();
#pragma unroll
    for (int kc = 0; kc < 2; ++kc) {
      short8 af[4], bf[4];
#pragma unroll
      for (int mi = 0; mi < 4; ++mi) {
        int row = wm + mi * 16 + l15;
        af[mi] = As[row][(kc * 4 + quad) ^ (row & 7)];
      }
#pragma unroll
      for (int ni = 0; ni < 4; ++ni) {
        int row = wn + ni * 16 + l15;
        bf[ni] = Bs[row][(kc * 4 + quad) ^ (row & 7)];
      }
#pragma unroll
      for (int mi = 0; mi < 4; ++mi)
#pragma unroll
        for (int ni = 0; ni < 4; ++ni)
          acc[mi][ni] = MFMA16(af[mi], bf[ni], acc[mi][ni]);
    }
  }

  // bias per output column (4 distinct cols per thread)
  float bcol[4];
#pragma unroll
  for (int ni = 0; ni < 4; ++ni) bcol[ni] = bias[colBase + wn + ni * 16 + l15];

  if (EPI == 0) {
    const int which = colBase >> 10;          // 0=Q 1=K 2=V (tile never straddles)
    const int b = rowBase >> 11;              // batch (tile within one batch)
    const int tt0 = rowBase & 2047;
    const int n1base = colBase & 1023;
    // Q pre-scaled so attn computes p = exp2(score) with no per-element fma
    const float osc = (which == 0) ? 0.180336880111f : 1.0f;  // 0.125*log2(e)
    __syncthreads();                          // staging reads done; reuse LDS
    if (which != 2) {
#pragma unroll
      for (int mi = 0; mi < 4; ++mi)
#pragma unroll
        for (int ni = 0; ni < 4; ++ni)
#pragma unroll
          for (int r = 0; r < 4; ++r)
            C16[wm + mi * 16 + quad * 4 + r][wn + ni * 16 + l15] =
                bf16u((acc[mi][ni][r] + bcol[ni]) * osc);
    } else {  // transposed: C16[col][row] so Vt stores are row-contiguous
#pragma unroll
      for (int mi = 0; mi < 4; ++mi)
#pragma unroll
        for (int ni = 0; ni < 4; ++ni)
#pragma unroll
          for (int r = 0; r < 4; ++r)
            C16[wn + ni * 16 + l15][wm + mi * 16 + quad * 4 + r] =
                bf16u(acc[mi][ni][r] + bcol[ni]);
    }
    __syncthreads();
    unsigned short* o = (unsigned short*)(which == 0 ? o0 : which == 1 ? o1 : o2);
    if (which != 2) {
      // Q/K[B,H,T,64]: row t, chunks 0..7 head h0, 8..15 head h0+1
#pragma unroll
      for (int j = 0; j < 8; ++j) {
        int flat = j * 256 + tid;
        int trow = flat >> 4, ch = flat & 15;
        int h = (n1base + ((ch & 8) << 3)) >> 6;
        long addr = ((long)((b * 16 + h) * 2048 + tt0 + trow)) * 64 + (ch & 7) * 8;
        *(short8*)&o[addr] = *(const short8*)&C16[trow][ch * 8];
      }
    } else {
      // Vt[B,H,64,T]: LDS row = d-col, chunks along t
#pragma unroll
      for (int j = 0; j < 8; ++j) {
        int flat = j * 256 + tid;
        int dcol = flat >> 4, ch = flat & 15;
        int h = (n1base + (dcol & 64)) >> 6;
        long addr = ((long)((b * 16 + h) * 64 + (dcol & 63))) * 2048 + tt0 + ch * 8;
        *(short8*)&o[addr] = *(const short8*)&C16[dcol][ch * 8];
      }
    }
  } else {
    // fp32 out: two half-tile passes (64x128 fp32 = 33 KB fits LDS)
    float* out = (float*)o0;
    for (int p = 0; p < 2; ++p) {
      __syncthreads();
      if ((w >> 1) == p) {
#pragma unroll
        for (int mi = 0; mi < 4; ++mi)
#pragma unroll
          for (int ni = 0; ni < 4; ++ni)
#pragma unroll
            for (int r = 0; r < 4; ++r)
              C32[mi * 16 + quad * 4 + r][wn + ni * 16 + l15] =
                  acc[mi][ni][r] + bcol[ni];
      }
      __syncthreads();
#pragma unroll
      for (int j = 0; j < 8; ++j) {
        int flat = j * 256 + tid;
        int row = flat >> 5, ch = flat & 31;
        float4 v4 = *(const float4*)&C32[row][ch * 4];
        *(float4*)&out[(long)(rowBase + p * 64 + row) * N + colBase + ch * 4] = v4;
      }
    }
  }
}

// ---------------- flash attention: 32x32x16 MFMA, 32 q/wave, 4 waves/block ----------------
// S^T = K.Q^T per 64-key tile (two 32x32 groups); Q pre-scaled, so
// p = exp2(z) exactly (static-offset softmax, offset 0; cancels in p/l).
// P redistributed C-layout -> B-frag in registers via v_permlane32_swap_b32.
// O^T += V^T.P^T. K/V LDS: proven [2][64][8] layout, chunk XOR'd by row&7.
__global__ __launch_bounds__(256, 4) void attn_kernel(
    const __hip_bfloat16* __restrict__ Q, const __hip_bfloat16* __restrict__ K,
    const __hip_bfloat16* __restrict__ Vt, __hip_bfloat16* __restrict__ Y, int T) {
  __shared__ short8 Ks[2][64][8];   // 16 KB
  __shared__ short8 Vs[2][64][8];   // 16 KB
  const int tid = threadIdx.x;
  const int w = tid >> 6, lane = tid & 63;
  const int c31 = lane & 31, half = lane >> 5;
  const int rsw = c31 & 7;                    // row&7 for frag reads
  const int idx = blockIdx.x;
  const int bh = idx & 63;                    // same-bh blocks share an XCD (idx%8)
  const int b = bh >> 4, h = bh & 15;
  const int qsel = idx >> 6;
  // work-balance permutation: stride-4 groups {15,8,4,3}{14,9,5,2}{13,10,6,1}{12,11,7,0}
  // each sum 30 -> uniform per-CU work under stride-256 block->CU assignment; heavy first.
  const int qq = qsel >> 2, qp = qsel & 3;
  const int jt = (qq == 0) ? 15 - qp : (qq == 1) ? 8 + qp : (qq == 2) ? 4 + qp : 3 - qp;

  const int qrow0 = jt * 128 + w * 32;
  const __hip_bfloat16* Qp = Q + (long)bh * T * 64;
  const __hip_bfloat16* Kp = K + (long)bh * T * 64;
  const __hip_bfloat16* Vp = Vt + (long)bh * 64 * T;

  // DMA staging: wave w stages rows w*16..w*16+15 of both K and V (2 calls each)
  const int sr8 = lane >> 3;                  // row within 8-row slab
  const int scc = (lane & 7) ^ sr8;           // source chunk = dest chunk ^ (row&7)

  // Q as B-frags of Q^T: col=q=c31, k(d) = s*16 + half*8 + j  (held whole loop)
  short8 qf[4];
#pragma unroll
  for (int s = 0; s < 4; ++s)
    qf[s] = *(const short8*)(Qp + (qrow0 + c31) * 64 + s * 16 + half * 8);

  f32x16 czero;                               // const-zero C operand (D != C)
#pragma unroll
  for (int i = 0; i < 16; ++i) czero[i] = 0.f;
  f32x16 oacc[2];
#pragma unroll
  for (int g = 0; g < 2; ++g) oacc[g] = czero;
  float lsum = 0.f;
  const int myq = qrow0 + c31;
  const int nkt = 2 * jt + 2;                    // block-uniform tile count
  const int my_nkt = 2 * jt + 1 + (w >> 1);      // this wave's useful tiles
  const int my_diag = my_nkt - 1;

#define STAGE_ATTN(buf, kbase)                                                 \
  do {                                                                         \
    const int rb_ = w * 16;                                                    \
    gload_lds16(Kp + ((kbase) + rb_ + sr8) * 64 + scc * 8, &Ks[buf][rb_][0]);  \
    gload_lds16(Kp + ((kbase) + rb_ + 8 + sr8) * 64 + scc * 8,                 \
                &Ks[buf][rb_ + 8][0]);                                         \
    gload_lds16(Vp + (long)(rb_ + sr8) * T + (kbase) + scc * 8,                \
                &Vs[buf][rb_][0]);                                             \
    gload_lds16(Vp + (long)(rb_ + 8 + sr8) * T + (kbase) + scc * 8,            \
                &Vs[buf][rb_ + 8][0]);                                         \
  } while (0)

  STAGE_ATTN(0, 0);
  __syncthreads();

  for (int kt = 0; kt < nkt; ++kt) {
    const int bb = kt & 1;
    const int kb = kt * 64;
    if (kt + 1 < nkt) STAGE_ATTN(bb ^ 1, kb + 64);  // async DMA into spare buffer

    if (kt < my_nkt) {
      short8 pb[4];  // P^T B-frags, keys S*16 + half*8 + j
#pragma unroll
      for (int g = 0; g < 2; ++g) {
        // ---- S^T(32 keys x 32 q) = K.Q^T (first MFMA reads czero, writes fresh z) ----
        f32x16 z = MFMA32(Ks[bb][g * 32 + c31][half ^ rsw], qf[0], czero);
#pragma unroll
        for (int s = 1; s < 4; ++s) {
          short8 af = Ks[bb][g * 32 + c31][(s * 2 + half) ^ rsw];
          z = MFMA32(af, qf[s], z);
        }
        // causal mask: only the diagonal tile (wave-uniform branch)
        if (kt == my_diag) {
#pragma unroll
          for (int r = 0; r < 16; ++r) {
            int key = kb + g * 32 + (r & 3) + 8 * (r >> 2) + 4 * half;
            if (key > myq) z[r] = -INFINITY;  // exp2 -> 0
          }
        }
        // ---- softmax: p = exp2(z), pack pairs via v_perm (proven path) ----
        unsigned pk[8];
#pragma unroll
        for (int i = 0; i < 8; ++i) {
          float p0 = EXP2(z[2 * i]);
          float p1 = EXP2(z[2 * i + 1]);
          lsum += p0 + p1;
          pk[i] = pack_bf16x2(p0, p1);  // keys 8*(i>>1)+4*half+2*(i&1), +1
        }
        // ---- C-layout -> B-frag via permlane32_swap (no LDS) ----
        // word j2 of slice s: keys s*16 + half*8 + 2*j2,+1.
        // swap(pk[4s+j'], pk[4s+2+j']) -> new_a = word j', new_b = word j'+2.
#pragma unroll
        for (int s = 0; s < 2; ++s) {
          auto r0 = __builtin_amdgcn_permlane32_swap(pk[4 * s + 0], pk[4 * s + 2],
                                                     false, false);
          auto r1 = __builtin_amdgcn_permlane32_swap(pk[4 * s + 1], pk[4 * s + 3],
                                                     false, false);
          union { unsigned u[4]; short8 s8; } cv;
          cv.u[0] = r0[0]; cv.u[1] = r1[0]; cv.u[2] = r0[1]; cv.u[3] = r1[1];
          pb[g * 2 + s] = cv.s8;
        }
      }
      // ---- O^T(64 d x 32 q) += V^T.P^T ----
#pragma unroll
      for (int dg = 0; dg < 2; ++dg)
#pragma unroll
        for (int S = 0; S < 4; ++S) {
          short8 vf = Vs[bb][dg * 32 + c31][(S * 2 + half) ^ rsw];
          oacc[dg] = MFMA32(vf, pb[S], oacc[dg]);
        }
    }
    __syncthreads();   // drains DMA (vmcnt) + protects LDS buffers
  }

  // halves hold complementary key subsets for the same q column
  lsum += __shfl_xor(lsum, 32);

  // O^T: d = dg*32 + (reg&3) + 8*(reg>>2) + 4*half, q = c31
  const float inv = 1.0f / lsum;
  unsigned short* Yu = (unsigned short*)Y;
  const long rowoff = ((long)(b * 2048 + qrow0 + c31)) * 1024 + h * 64;
#pragma unroll
  for (int dg = 0; dg < 2; ++dg)
#pragma unroll
    for (int rg = 0; rg < 4; ++rg) {
      uint2 o;
      o.x = pack_bf16x2(oacc[dg][rg * 4 + 0] * inv, oacc[dg][rg * 4 + 1] * inv);
      o.y = pack_bf16x2(oacc[dg][rg * 4 + 2] * inv, oacc[dg][rg * 4 + 3] * inv);
      *(uint2*)&Yu[rowoff + dg * 32 + half * 4 + rg * 8] = o;
    }
}

extern "C" void kernel_launch(void* const* d_in, const int* in_sizes, int n_in,
                              void* d_out, int out_size, void* d_ws, size_t ws_size,
                              hipStream_t stream) {
  const float* x  = (const float*)d_in[0];   // [4,2048,1024]
  const float* Wa = (const float*)d_in[1];   // [1024,3072]
  const float* ba = (const float*)d_in[2];   // [3072]
  const float* Wp = (const float*)d_in[3];   // [1024,1024]
  const float* bp = (const float*)d_in[4];   // [1024]
  float* out = (float*)d_out;                // [4,2048,1024] fp32

  char* ws = (char*)d_ws;
  __hip_bfloat16* Xb  = (__hip_bfloat16*)(ws);              // [8192,1024]
  __hip_bfloat16* WaT = (__hip_bfloat16*)(ws + 16777216);   // [3072,1024]
  __hip_bfloat16* WpT = (__hip_bfloat16*)(ws + 23068672);   // [1024,1024]
  __hip_bfloat16* Qb  = (__hip_bfloat16*)(ws + 25165824);   // [B,H,T,Dh]
  __hip_bfloat16* Kb  = (__hip_bfloat16*)(ws + 41943040);   // [B,H,T,Dh]
  __hip_bfloat16* Vtb = (__hip_bfloat16*)(ws + 58720256);   // [B,H,Dh,T]
  __hip_bfloat16* Yb  = (__hip_bfloat16*)(ws + 75497472);   // [8192,1024]
  if (ws_size < 92274688) return;

  conv_f32_bf16<<<8192, 256, 0, stream>>>(x, (unsigned*)Xb, 2097152);
  transpose_bf16<<<dim3(96, 32), dim3(32, 8), 0, stream>>>(Wa, WaT, 1024, 3072);
  transpose_bf16<<<dim3(32, 32), dim3(32, 8), 0, stream>>>(Wp, WpT, 1024, 1024);
  gemm_bt<0><<<dim3(24, 64), 256, 0, stream>>>(Xb, WaT, ba, Qb, Kb, Vtb, 3072, 1024);
  attn_kernel<<<dim3(1024), dim3(256), 0, stream>>>(Qb, Kb, Vtb, Yb, 2048);
  gemm_bt<1><<<dim3(8, 64), 256, 0, stream>>>(Yb, WpT, bp, out, nullptr, nullptr, 1024, 1024);
}

// Round 6
// 222.697 us; speedup vs baseline: 1.0366x; 1.0366x over previous
//
#include <hip/hip_runtime.h>
#include <hip/hip_bf16.h>

// MHA forward: B=4, T=2048, N=1024, H=16, Dh=64.
// Round 15 (= R14 resubmitted after infra failure):
//  - prep_kernel: conv + both weight transposes fused (one launch, not three).
//  - attn: 3-buffer K/V staging, prefetch distance 2, counted s_waitcnt vmcnt(4)
//    (one tile always in flight across the barrier; DMA latency hides under a
//    full iteration). Order per iter: wait -> s_barrier -> STAGE(kt+2) -> compute.
//  - keeps R13's verified VALU diet (Q pre-scaled, p=exp2(z), czero C-operand,
//    v_perm packs only; NO inline-asm cvt_pk -- that was the R11/R12 NaN).

typedef __attribute__((ext_vector_type(8))) short short8;   // 8 x bf16 (4 VGPR)
typedef __attribute__((ext_vector_type(4))) float f32x4;
typedef __attribute__((ext_vector_type(16))) float f32x16;

#define MFMA16(a, b, c) __builtin_amdgcn_mfma_f32_16x16x32_bf16((a), (b), (c), 0, 0, 0)
#define MFMA32(a, b, c) __builtin_amdgcn_mfma_f32_32x32x16_bf16((a), (b), (c), 0, 0, 0)

#if defined(__has_builtin)
#if __has_builtin(__builtin_amdgcn_exp2f)
#define EXP2(x) __builtin_amdgcn_exp2f(x)
#endif
#endif
#ifndef EXP2
#define EXP2(x) exp2f(x)
#endif

// async global->LDS, 16B per lane; LDS dest = wave-uniform base + lane*16
__device__ __forceinline__ void gload_lds16(const void* g, void* l) {
  __builtin_amdgcn_global_load_lds(
      (const __attribute__((address_space(1))) unsigned int*)g,
      (__attribute__((address_space(3))) unsigned int*)l, 16, 0, 0);
}

// pack two fp32 -> bf16x2 (round via bit bias + byte perm)
__device__ __forceinline__ unsigned pack_bf16x2(float lo, float hi) {
  unsigned ulo = __float_as_uint(lo) + 0x8000u;
  unsigned uhi = __float_as_uint(hi) + 0x8000u;
  return __builtin_amdgcn_perm(uhi, ulo, 0x07060302u);
}

__device__ __forceinline__ unsigned short bf16u(float f) {
  return (unsigned short)((__float_as_uint(f) + 0x8000u) >> 16);
}

// ---------------- fused prep: Wa transpose | Wp transpose | x fp32->bf16 ----------------
__global__ void prep_kernel(const float* __restrict__ x, unsigned* __restrict__ Xb,
                            const float* __restrict__ Wa, __hip_bfloat16* __restrict__ WaT,
                            const float* __restrict__ Wp, __hip_bfloat16* __restrict__ WpT) {
  __shared__ float tile[32][33];
  const int tid = threadIdx.x;
  int blk = blockIdx.x;
  if (blk >= 4096) {
    // conv: x[2097152 float4] -> Xb (bf16)
    int i = (blk - 4096) * 256 + tid;
    float4 v = ((const float4*)x)[i];
    uint2 o;
    o.x = pack_bf16x2(v.x, v.y);
    o.y = pack_bf16x2(v.z, v.w);
    ((uint2*)Xb)[i] = o;
    return;
  }
  // transpose+convert: dst[c][r] = bf16(src[r][c])
  const float* src;
  __hip_bfloat16* dst;
  int R, C, bx, by;
  if (blk < 3072) {
    src = Wa; dst = WaT; R = 1024; C = 3072; bx = blk % 96; by = blk / 96;
  } else {
    blk -= 3072;
    src = Wp; dst = WpT; R = 1024; C = 1024; bx = blk & 31; by = blk >> 5;
  }
  const int tx = tid & 31, ty = tid >> 5;        // logical (32, 8)
  const int c0 = bx * 32, r0 = by * 32;
#pragma unroll
  for (int i = 0; i < 32; i += 8)
    tile[ty + i][tx] = src[(long)(r0 + ty + i) * C + c0 + tx];
  __syncthreads();
#pragma unroll
  for (int i = 0; i < 32; i += 8)
    dst[(long)(c0 + ty + i) * R + r0 + tx] = __float2bfloat16(tile[tx][ty + i]);
}

// ---------------- GEMM: C[M,N] = A[M,K] @ Bt[N,K]^T + bias ----------------
// K-loop: m97 structure (barrier / global_load_lds / barrier / MFMA).
// Epilogue: C -> LDS (bias added; V-tiles transposed; Q scaled by 0.125*log2e)
// -> 16B coalesced stores.
template <int EPI>
__global__ __launch_bounds__(256, 2) void gemm_bt(
    const __hip_bfloat16* __restrict__ A, const __hip_bfloat16* __restrict__ Bt,
    const float* __restrict__ bias, void* o0, void* o1, void* o2, int N, int K) {
  __shared__ alignas(16) char smem[34816];
  short8 (*As)[8] = (short8(*)[8])smem;                        // [128][8]
  short8 (*Bs)[8] = (short8(*)[8])(smem + 16384);              // [128][8]
  unsigned short (*C16)[136] = (unsigned short(*)[136])smem;   // [128][136]
  float (*C32)[132] = (float(*)[132])smem;                     // [64][132]

  const int tid = threadIdx.x;
  const int lane = tid & 63, w = tid >> 6;
  const int l15 = lane & 15, quad = lane >> 4;
  const int wm = (w >> 1) * 64, wn = (w & 1) * 64;
  const int rowBase = blockIdx.y * 128;
  const int colBase = blockIdx.x * 128;
  const int sr8 = lane >> 3;                  // 0..7 within wave's 8-row slab
  const int scc = (lane & 7) ^ sr8;           // source chunk (dest chunk ^ row&7)

  f32x4 acc[4][4];
#pragma unroll
  for (int mi = 0; mi < 4; ++mi)
#pragma unroll
    for (int ni = 0; ni < 4; ++ni)
      acc[mi][ni] = {0.f, 0.f, 0.f, 0.f};

  for (int k0 = 0; k0 < K; k0 += 64) {
    __syncthreads();
#pragma unroll
    for (int p = 0; p < 4; ++p) {
      const int rb = p * 32 + w * 8;          // wave-uniform row base
      const int row = rb + sr8;
      gload_lds16(A + (rowBase + row) * K + k0 + scc * 8, &As[rb][0]);
      gload_lds16(Bt + (colBase + row) * K + k0 + scc * 8, &Bs[rb][0]);
    }
    __syncthreads();
#pragma unroll
    for (int kc = 0; kc < 2; ++kc) {
      short8 af[4], bf[4];
#pragma unroll
      for (int mi = 0; mi < 4; ++mi) {
        int row = wm + mi * 16 + l15;
        af[mi] = As[row][(kc * 4 + quad) ^ (row & 7)];
      }
#pragma unroll
      for (int ni = 0; ni < 4; ++ni) {
        int row = wn + ni * 16 + l15;
        bf[ni] = Bs[row][(kc * 4 + quad) ^ (row & 7)];
      }
#pragma unroll
      for (int mi = 0; mi < 4; ++mi)
#pragma unroll
        for (int ni = 0; ni < 4; ++ni)
          acc[mi][ni] = MFMA16(af[mi], bf[ni], acc[mi][ni]);
    }
  }

  // bias per output column (4 distinct cols per thread)
  float bcol[4];
#pragma unroll
  for (int ni = 0; ni < 4; ++ni) bcol[ni] = bias[colBase + wn + ni * 16 + l15];

  if (EPI == 0) {
    const int which = colBase >> 10;          // 0=Q 1=K 2=V (tile never straddles)
    const int b = rowBase >> 11;              // batch (tile within one batch)
    const int tt0 = rowBase & 2047;
    const int n1base = colBase & 1023;
    // Q pre-scaled so attn computes p = exp2(score) with no per-element fma
    const float osc = (which == 0) ? 0.180336880111f : 1.0f;  // 0.125*log2(e)
    __syncthreads();                          // staging reads done; reuse LDS
    if (which != 2) {
#pragma unroll
      for (int mi = 0; mi < 4; ++mi)
#pragma unroll
        for (int ni = 0; ni < 4; ++ni)
#pragma unroll
          for (int r = 0; r < 4; ++r)
            C16[wm + mi * 16 + quad * 4 + r][wn + ni * 16 + l15] =
                bf16u((acc[mi][ni][r] + bcol[ni]) * osc);
    } else {  // transposed: C16[col][row] so Vt stores are row-contiguous
#pragma unroll
      for (int mi = 0; mi < 4; ++mi)
#pragma unroll
        for (int ni = 0; ni < 4; ++ni)
#pragma unroll
          for (int r = 0; r < 4; ++r)
            C16[wn + ni * 16 + l15][wm + mi * 16 + quad * 4 + r] =
                bf16u(acc[mi][ni][r] + bcol[ni]);
    }
    __syncthreads();
    unsigned short* o = (unsigned short*)(which == 0 ? o0 : which == 1 ? o1 : o2);
    if (which != 2) {
      // Q/K[B,H,T,64]: row t, chunks 0..7 head h0, 8..15 head h0+1
#pragma unroll
      for (int j = 0; j < 8; ++j) {
        int flat = j * 256 + tid;
        int trow = flat >> 4, ch = flat & 15;
        int h = (n1base + ((ch & 8) << 3)) >> 6;
        long addr = ((long)((b * 16 + h) * 2048 + tt0 + trow)) * 64 + (ch & 7) * 8;
        *(short8*)&o[addr] = *(const short8*)&C16[trow][ch * 8];
      }
    } else {
      // Vt[B,H,64,T]: LDS row = d-col, chunks along t
#pragma unroll
      for (int j = 0; j < 8; ++j) {
        int flat = j * 256 + tid;
        int dcol = flat >> 4, ch = flat & 15;
        int h = (n1base + (dcol & 64)) >> 6;
        long addr = ((long)((b * 16 + h) * 64 + (dcol & 63))) * 2048 + tt0 + ch * 8;
        *(short8*)&o[addr] = *(const short8*)&C16[dcol][ch * 8];
      }
    }
  } else {
    // fp32 out: two half-tile passes (64x128 fp32 = 33 KB fits LDS)
    float* out = (float*)o0;
    for (int p = 0; p < 2; ++p) {
      __syncthreads();
      if ((w >> 1) == p) {
#pragma unroll
        for (int mi = 0; mi < 4; ++mi)
#pragma unroll
          for (int ni = 0; ni < 4; ++ni)
#pragma unroll
            for (int r = 0; r < 4; ++r)
              C32[mi * 16 + quad * 4 + r][wn + ni * 16 + l15] =
                  acc[mi][ni][r] + bcol[ni];
      }
      __syncthreads();
#pragma unroll
      for (int j = 0; j < 8; ++j) {
        int flat = j * 256 + tid;
        int row = flat >> 5, ch = flat & 31;
        float4 v4 = *(const float4*)&C32[row][ch * 4];
        *(float4*)&out[(long)(rowBase + p * 64 + row) * N + colBase + ch * 4] = v4;
      }
    }
  }
}

// ---------------- flash attention: 32x32x16 MFMA, 32 q/wave, 4 waves/block ----------------
// S^T = K.Q^T per 64-key tile; Q pre-scaled so p = exp2(z) exactly.
// P redistributed C-layout -> B-frag in registers via v_permlane32_swap_b32.
// O^T += V^T.P^T. K/V: 3 LDS buffers, prefetch distance 2, counted vmcnt.
// Per iter: wait vmcnt(4|0) -> s_barrier -> STAGE(kt+2) -> compute(kt).
// Race-check: STAGE(kt+2) targets buf (kt+2)%3; last reader was compute(kt-1),
// which all waves finished before the barrier this iteration. vmcnt(4) leaves
// exactly one tile (4 DMA calls) in flight across the barrier.
__global__ __launch_bounds__(256, 3) void attn_kernel(
    const __hip_bfloat16* __restrict__ Q, const __hip_bfloat16* __restrict__ K,
    const __hip_bfloat16* __restrict__ Vt, __hip_bfloat16* __restrict__ Y, int T) {
  __shared__ short8 Ks[3][64][8];   // 24 KB
  __shared__ short8 Vs[3][64][8];   // 24 KB
  const int tid = threadIdx.x;
  const int w = tid >> 6, lane = tid & 63;
  const int c31 = lane & 31, half = lane >> 5;
  const int rsw = c31 & 7;                    // row&7 for frag reads
  const int idx = blockIdx.x;
  const int bh = idx & 63;                    // same-bh blocks share an XCD (idx%8)
  const int b = bh >> 4, h = bh & 15;
  const int qsel = idx >> 6;
  // work-balance permutation: stride-4 groups {15,8,4,3}{14,9,5,2}{13,10,6,1}{12,11,7,0}
  // each sum 30 -> uniform per-CU work under stride-256 block->CU assignment; heavy first.
  const int qq = qsel >> 2, qp = qsel & 3;
  const int jt = (qq == 0) ? 15 - qp : (qq == 1) ? 8 + qp : (qq == 2) ? 4 + qp : 3 - qp;

  const int qrow0 = jt * 128 + w * 32;
  const __hip_bfloat16* Qp = Q + (long)bh * T * 64;
  const __hip_bfloat16* Kp = K + (long)bh * T * 64;
  const __hip_bfloat16* Vp = Vt + (long)bh * 64 * T;

  // DMA staging: wave w stages rows w*16..w*16+15 of both K and V (2 calls each)
  const int sr8 = lane >> 3;                  // row within 8-row slab
  const int scc = (lane & 7) ^ sr8;           // source chunk = dest chunk ^ (row&7)

  // Q as B-frags of Q^T: col=q=c31, k(d) = s*16 + half*8 + j  (held whole loop)
  short8 qf[4];
#pragma unroll
  for (int s = 0; s < 4; ++s)
    qf[s] = *(const short8*)(Qp + (qrow0 + c31) * 64 + s * 16 + half * 8);

  f32x16 czero;                               // const-zero C operand (D != C)
#pragma unroll
  for (int i = 0; i < 16; ++i) czero[i] = 0.f;
  f32x16 oacc[2];
#pragma unroll
  for (int g = 0; g < 2; ++g) oacc[g] = czero;
  float lsum = 0.f;
  const int myq = qrow0 + c31;
  const int nkt = 2 * jt + 2;                    // block-uniform tile count (>= 2)
  const int my_nkt = 2 * jt + 1 + (w >> 1);      // this wave's useful tiles
  const int my_diag = my_nkt - 1;

#define STAGE_ATTN(buf, kbase)                                                 \
  do {                                                                         \
    const int rb_ = w * 16;                                                    \
    gload_lds16(Kp + ((kbase) + rb_ + sr8) * 64 + scc * 8, &Ks[buf][rb_][0]);  \
    gload_lds16(Kp + ((kbase) + rb_ + 8 + sr8) * 64 + scc * 8,                 \
                &Ks[buf][rb_ + 8][0]);                                         \
    gload_lds16(Vp + (long)(rb_ + sr8) * T + (kbase) + scc * 8,                \
                &Vs[buf][rb_][0]);                                             \
    gload_lds16(Vp + (long)(rb_ + 8 + sr8) * T + (kbase) + scc * 8,            \
                &Vs[buf][rb_ + 8][0]);                                         \
  } while (0)

  STAGE_ATTN(0, 0);
  STAGE_ATTN(1, 64);        // nkt >= 2 always; keys 64..127 <= T
  int bcur = 0;             // buffer holding tile kt

  for (int kt = 0; kt < nkt; ++kt) {
    // tile kt's DMA (4 calls) complete; allow the newer tile's 4 to stay in flight
    if (kt < nkt - 1)
      asm volatile("s_waitcnt vmcnt(4)" ::: "memory");
    else
      asm volatile("s_waitcnt vmcnt(0)" ::: "memory");
    __builtin_amdgcn_s_barrier();
    __builtin_amdgcn_sched_barrier(0);

    if (kt + 2 < nkt) {
      const int bs = (bcur >= 1) ? bcur - 1 : 2;   // (kt+2)%3
      STAGE_ATTN(bs, (kt + 2) * 64);
    }

    if (kt < my_nkt) {
      const int kb = kt * 64;
      short8 pb[4];  // P^T B-frags, keys S*16 + half*8 + j
#pragma unroll
      for (int g = 0; g < 2; ++g) {
        // ---- S^T(32 keys x 32 q) = K.Q^T (first MFMA reads czero, writes fresh z) ----
        f32x16 z = MFMA32(Ks[bcur][g * 32 + c31][half ^ rsw], qf[0], czero);
#pragma unroll
        for (int s = 1; s < 4; ++s) {
          short8 af = Ks[bcur][g * 32 + c31][(s * 2 + half) ^ rsw];
          z = MFMA32(af, qf[s], z);
        }
        // causal mask: only the diagonal tile (wave-uniform branch)
        if (kt == my_diag) {
#pragma unroll
          for (int r = 0; r < 16; ++r) {
            int key = kb + g * 32 + (r & 3) + 8 * (r >> 2) + 4 * half;
            if (key > myq) z[r] = -INFINITY;  // exp2 -> 0
          }
        }
        // ---- softmax: p = exp2(z), pack pairs via v_perm (proven path) ----
        unsigned pk[8];
#pragma unroll
        for (int i = 0; i < 8; ++i) {
          float p0 = EXP2(z[2 * i]);
          float p1 = EXP2(z[2 * i + 1]);
          lsum += p0 + p1;
          pk[i] = pack_bf16x2(p0, p1);  // keys 8*(i>>1)+4*half+2*(i&1), +1
        }
        // ---- C-layout -> B-frag via permlane32_swap (no LDS) ----
#pragma unroll
        for (int s = 0; s < 2; ++s) {
          auto r0 = __builtin_amdgcn_permlane32_swap(pk[4 * s + 0], pk[4 * s + 2],
                                                     false, false);
          auto r1 = __builtin_amdgcn_permlane32_swap(pk[4 * s + 1], pk[4 * s + 3],
                                                     false, false);
          union { unsigned u[4]; short8 s8; } cv;
          cv.u[0] = r0[0]; cv.u[1] = r1[0]; cv.u[2] = r0[1]; cv.u[3] = r1[1];
          pb[g * 2 + s] = cv.s8;
        }
      }
      // ---- O^T(64 d x 32 q) += V^T.P^T ----
#pragma unroll
      for (int dg = 0; dg < 2; ++dg)
#pragma unroll
        for (int S = 0; S < 4; ++S) {
          short8 vf = Vs[bcur][dg * 32 + c31][(S * 2 + half) ^ rsw];
          oacc[dg] = MFMA32(vf, pb[S], oacc[dg]);
        }
    }
    bcur = (bcur == 2) ? 0 : bcur + 1;
  }

  // halves hold complementary key subsets for the same q column
  lsum += __shfl_xor(lsum, 32);

  // O^T: d = dg*32 + (reg&3) + 8*(reg>>2) + 4*half, q = c31
  const float inv = 1.0f / lsum;
  unsigned short* Yu = (unsigned short*)Y;
  const long rowoff = ((long)(b * 2048 + qrow0 + c31)) * 1024 + h * 64;
#pragma unroll
  for (int dg = 0; dg < 2; ++dg)
#pragma unroll
    for (int rg = 0; rg < 4; ++rg) {
      uint2 o;
      o.x = pack_bf16x2(oacc[dg][rg * 4 + 0] * inv, oacc[dg][rg * 4 + 1] * inv);
      o.y = pack_bf16x2(oacc[dg][rg * 4 + 2] * inv, oacc[dg][rg * 4 + 3] * inv);
      *(uint2*)&Yu[rowoff + dg * 32 + half * 4 + rg * 8] = o;
    }
}

extern "C" void kernel_launch(void* const* d_in, const int* in_sizes, int n_in,
                              void* d_out, int out_size, void* d_ws, size_t ws_size,
                              hipStream_t stream) {
  const float* x  = (const float*)d_in[0];   // [4,2048,1024]
  const float* Wa = (const float*)d_in[1];   // [1024,3072]
  const float* ba = (const float*)d_in[2];   // [3072]
  const float* Wp = (const float*)d_in[3];   // [1024,1024]
  const float* bp = (const float*)d_in[4];   // [1024]
  float* out = (float*)d_out;                // [4,2048,1024] fp32

  char* ws = (char*)d_ws;
  __hip_bfloat16* Xb  = (__hip_bfloat16*)(ws);              // [8192,1024]
  __hip_bfloat16* WaT = (__hip_bfloat16*)(ws + 16777216);   // [3072,1024]
  __hip_bfloat16* WpT = (__hip_bfloat16*)(ws + 23068672);   // [1024,1024]
  __hip_bfloat16* Qb  = (__hip_bfloat16*)(ws + 25165824);   // [B,H,T,Dh]
  __hip_bfloat16* Kb  = (__hip_bfloat16*)(ws + 41943040);   // [B,H,T,Dh]
  __hip_bfloat16* Vtb = (__hip_bfloat16*)(ws + 58720256);   // [B,H,Dh,T]
  __hip_bfloat16* Yb  = (__hip_bfloat16*)(ws + 75497472);   // [8192,1024]
  if (ws_size < 92274688) return;

  prep_kernel<<<12288, 256, 0, stream>>>(x, (unsigned*)Xb, Wa, WaT, Wp, WpT);
  gemm_bt<0><<<dim3(24, 64), 256, 0, stream>>>(Xb, WaT, ba, Qb, Kb, Vtb, 3072, 1024);
  attn_kernel<<<dim3(1024), dim3(256), 0, stream>>>(Qb, Kb, Vtb, Yb, 2048);
  gemm_bt<1><<<dim3(8, 64), 256, 0, stream>>>(Yb, WpT, bp, out, nullptr, nullptr, 1024, 1024);
}